// Round 2
// baseline (1161.898 us; speedup 1.0000x reference)
//
#include <hip/hip_runtime.h>

typedef unsigned short u16;
typedef unsigned int u32;
typedef __bf16 bf16x8 __attribute__((ext_vector_type(8)));
typedef float f32x4 __attribute__((ext_vector_type(4)));
typedef u16 u16x8 __attribute__((ext_vector_type(8)));

#define NTOK 8192
#define CDIM 1024
#define NEXP 8
#define FEDIM 1024
#define FSDIM 4096

#define GLD16(gp, lp) __builtin_amdgcn_global_load_lds( \
    (const __attribute__((address_space(1))) void*)(gp), \
    (__attribute__((address_space(3))) void*)(lp), 16, 0, 0)

__device__ __forceinline__ u16 f2bf(float f) {
  u32 u = __float_as_uint(f);
  u += 0x7FFFu + ((u >> 16) & 1u);   // RNE
  return (u16)(u >> 16);
}
__device__ __forceinline__ float bf2f(u16 h) {
  return __uint_as_float(((u32)h) << 16);
}

// ---------------- gate: scores, softmax, top-2, expert lists, x->bf16 -------
// 256 blocks x 256 threads; each wave owns 8 consecutive tokens. Atomic
// traffic: 8 LDS atomics/token (fast) + 8 global atomics/BLOCK (chunk
// reservation) instead of 2 global atomics/token (round-1: 200us serialized).
__global__ __launch_bounds__(256) void gate_kernel(
    const float* __restrict__ x, const float* __restrict__ gw,
    float* __restrict__ scores, u16* __restrict__ xb, int* __restrict__ cnt,
    int* __restrict__ tok, float* __restrict__ wgt)
{
  __shared__ int lcnt[NEXP];
  __shared__ int lbase[NEXP];
  __shared__ int rec_i[32];
  __shared__ int rec_p1[32], rec_p2[32];
  __shared__ float rec_w1[32], rec_w2[32];

  int tid = threadIdx.x, wave = tid >> 6, lane = tid & 63;
  if (tid < NEXP) lcnt[tid] = 0;
  __syncthreads();

  int tbase = blockIdx.x * 32 + wave * 8;
#pragma unroll
  for (int it = 0; it < 8; ++it) {
    int n = tbase + it;
    const float4* xr = (const float4*)(x + (size_t)n * CDIM) + lane * 4;
    float4 xv[4];
#pragma unroll
    for (int j = 0; j < 4; j++) xv[j] = xr[j];
    // fused f32 -> bf16 conversion of x (lane holds elements [lane*16, lane*16+16))
    u16x8 rA, rB;
    rA[0]=f2bf(xv[0].x); rA[1]=f2bf(xv[0].y); rA[2]=f2bf(xv[0].z); rA[3]=f2bf(xv[0].w);
    rA[4]=f2bf(xv[1].x); rA[5]=f2bf(xv[1].y); rA[6]=f2bf(xv[1].z); rA[7]=f2bf(xv[1].w);
    rB[0]=f2bf(xv[2].x); rB[1]=f2bf(xv[2].y); rB[2]=f2bf(xv[2].z); rB[3]=f2bf(xv[2].w);
    rB[4]=f2bf(xv[3].x); rB[5]=f2bf(xv[3].y); rB[6]=f2bf(xv[3].z); rB[7]=f2bf(xv[3].w);
    u16* xrow = xb + (size_t)n * CDIM + lane * 16;
    *(u16x8*)xrow = rA;
    *(u16x8*)(xrow + 8) = rB;

    float s[NEXP];
#pragma unroll
    for (int e = 0; e < NEXP; e++) {
      const float4* g = (const float4*)(gw + (size_t)e * CDIM) + lane * 4;
      float a = 0.f;
#pragma unroll
      for (int j = 0; j < 4; j++) {
        float4 gv = g[j];
        a += xv[j].x * gv.x + xv[j].y * gv.y + xv[j].z * gv.z + xv[j].w * gv.w;
      }
#pragma unroll
      for (int o = 32; o > 0; o >>= 1) a += __shfl_xor(a, o);
      s[e] = a;
    }
    if (lane == 0) {
      float m = s[0];
      for (int e = 1; e < NEXP; e++) m = fmaxf(m, s[e]);
      float p[NEXP], sum = 0.f;
      for (int e = 0; e < NEXP; e++) { p[e] = __expf(s[e] - m); sum += p[e]; }
      int i1 = 0;
      for (int e = 1; e < NEXP; e++) if (p[e] > p[i1]) i1 = e;
      int i2 = (i1 == 0) ? 1 : 0;
      for (int e = 0; e < NEXP; e++) if (e != i1 && p[e] > p[i2]) i2 = e;
      float w1 = p[i1] / sum, w2 = p[i2] / sum;
#pragma unroll
      for (int e = 0; e < NEXP; e++) scores[(size_t)n * NEXP + e] = s[e];
      int p1 = atomicAdd(&lcnt[i1], 1);
      int p2 = atomicAdd(&lcnt[i2], 1);
      int slot = wave * 8 + it;
      rec_i[slot] = i1 | (i2 << 8);
      rec_p1[slot] = p1; rec_p2[slot] = p2;
      rec_w1[slot] = w1; rec_w2[slot] = w2;
    }
  }
  __syncthreads();
  if (tid < NEXP) lbase[tid] = atomicAdd(&cnt[tid], lcnt[tid]);
  __syncthreads();
  if (tid < 32) {
    int n = blockIdx.x * 32 + tid;
    int i1 = rec_i[tid] & 0xff, i2 = rec_i[tid] >> 8;
    int q1 = lbase[i1] + rec_p1[tid];
    int q2 = lbase[i2] + rec_p2[tid];
    tok[i1 * NTOK + q1] = n; wgt[i1 * NTOK + q1] = rec_w1[tid];
    tok[i2 * NTOK + q2] = n; wgt[i2 * NTOK + q2] = rec_w2[tid];
  }
}

__global__ void prefix_kernel(const int* __restrict__ cnt, int* __restrict__ prefix) {
  if (threadIdx.x == 0 && blockIdx.x == 0) {
    int a = 0;
    for (int e = 0; e < NEXP; e++) { prefix[e] = a; a += cnt[e]; }
    prefix[NEXP] = a;
  }
}

// ---------------- tiled transpose f32[R][C] -> bf16[C][R], batched in z ------
__global__ __launch_bounds__(256) void transpose_kernel(const float* __restrict__ src,
    u16* __restrict__ dst, int R, int C)
{
  __shared__ float tile[32][33];
  size_t base = (size_t)blockIdx.z * R * C;
  int c0 = blockIdx.x * 32, r0 = blockIdx.y * 32;
  int tx = threadIdx.x & 31, ty = threadIdx.x >> 5;
#pragma unroll
  for (int i = 0; i < 4; i++) {
    int r = ty + i * 8;
    tile[r][tx] = src[base + (size_t)(r0 + r) * C + c0 + tx];
  }
  __syncthreads();
#pragma unroll
  for (int i = 0; i < 4; i++) {
    int c = ty + i * 8;
    dst[base + (size_t)(c0 + c) * R + r0 + tx] = f2bf(tile[tx][c]);
  }
}

// ---------------- 128x128xBK32 bf16 MFMA GEMM (m97 structure) ----------------
// A: bf16 [*, lda] row-major.  B: bf16 B^T layout [ncols][ldb] (row n = output
// column n over K).  EPI: 0 store-bf16 g1, 1 SwiGLU(g1)*acc -> h, 2 store f32,
// 3 add f32, 4 scale-by-weight + atomicAdd scatter to out rows tok[].
// AMODE: 0 direct rows, 1 rows gathered via tok list (expert in/x),
//        2 rows at prefix[e]+r (expert h).
#define BM 128
#define BN 128
#define BK 32

template<int EPI, int AMODE>
__global__ __launch_bounds__(256) void gemm128(
    const u16* __restrict__ A, int lda,
    const u16* __restrict__ B, size_t bstride, int ldb,
    int M, int K,
    u16* __restrict__ g1, u16* __restrict__ hbuf, int ldg,
    float* __restrict__ outF, int ldo,
    const int* __restrict__ cnt, const int* __restrict__ prefix,
    const int* __restrict__ tok, const float* __restrict__ wgt)
{
  int e = blockIdx.z;
  // XCD-aware bijective swizzle (T1): grids here are all multiples of 8.
  int nwg = gridDim.x * gridDim.y;
  int bid = blockIdx.y * gridDim.x + blockIdx.x;
  int cpx = nwg >> 3;
  int swz = (bid & 7) * cpx + (bid >> 3);
  int bx = swz % gridDim.x, by = swz / gridDim.x;

  int Mloc = (AMODE == 0) ? M : cnt[e];
  int mbase = by * BM;
  if (AMODE != 0 && mbase >= Mloc) return;
  int nbase = bx * BN;
  int tid = threadIdx.x, wid = tid >> 6, lane = tid & 63;

  __shared__ __align__(16) u16 As[BM * BK];
  __shared__ __align__(16) u16 Bs[BN * BK];

  int sr = lane >> 2;             // 0..15 row within a 16-row staging group
  int kg = (lane & 3) * 8;        // k element offset (8 bf16 = 16B per lane)
  int arow0 = wid * 32 + sr;
  int arow1 = arow0 + 16;

  int pfx = (AMODE == 0) ? 0 : prefix[e];
  size_t r0, r1;
  if (AMODE == 0) {
    r0 = mbase + arow0; r1 = mbase + arow1;
  } else if (AMODE == 1) {
    r0 = tok[e * NTOK + min(mbase + arow0, Mloc - 1)];
    r1 = tok[e * NTOK + min(mbase + arow1, Mloc - 1)];
  } else {
    r0 = pfx + min(mbase + arow0, Mloc - 1);
    r1 = pfx + min(mbase + arow1, Mloc - 1);
  }

  const u16* Ap0 = A + r0 * (size_t)lda + kg;
  const u16* Ap1 = A + r1 * (size_t)lda + kg;
  const u16* Bb = B + ((AMODE != 0) ? (size_t)e * bstride : 0);
  const u16* Bp0 = Bb + (size_t)(nbase + arow0) * ldb + kg;
  const u16* Bp1 = Bb + (size_t)(nbase + arow1) * ldb + kg;

  u16* AsW0 = &As[(wid * 32) * BK];
  u16* AsW1 = &As[(wid * 32 + 16) * BK];
  u16* BsW0 = &Bs[(wid * 32) * BK];
  u16* BsW1 = &Bs[(wid * 32 + 16) * BK];

  int wr = wid >> 1, wc = wid & 1;
  int fr = lane & 15, fgk = (lane >> 4) * 8;

  f32x4 acc[4][4] = {};

  for (int k0 = 0; k0 < K; k0 += BK) {
    GLD16(Ap0, AsW0); GLD16(Ap1, AsW1);
    GLD16(Bp0, BsW0); GLD16(Bp1, BsW1);
    Ap0 += BK; Ap1 += BK; Bp0 += BK; Bp1 += BK;
    __syncthreads();   // drains vmcnt -> LDS tiles visible
    bf16x8 af[4], bfr[4];
#pragma unroll
    for (int m = 0; m < 4; m++)
      af[m] = *(const bf16x8*)&As[(wr * 64 + m * 16 + fr) * BK + fgk];
#pragma unroll
    for (int n = 0; n < 4; n++)
      bfr[n] = *(const bf16x8*)&Bs[(wc * 64 + n * 16 + fr) * BK + fgk];
#pragma unroll
    for (int m = 0; m < 4; m++)
#pragma unroll
      for (int n = 0; n < 4; n++)
        acc[m][n] = __builtin_amdgcn_mfma_f32_16x16x32_bf16(af[m], bfr[n], acc[m][n], 0, 0, 0);
    __syncthreads();
  }

  // epilogue — C/D layout: col = lane&15, row = (lane>>4)*4 + j  [m89-verified]
  int fg4 = (lane >> 4) * 4;
#pragma unroll
  for (int m = 0; m < 4; m++) {
#pragma unroll
    for (int j = 0; j < 4; j++) {
      int rloc = wr * 64 + m * 16 + fg4 + j;
      int rr = mbase + rloc;
      if (AMODE != 0 && rr >= Mloc) continue;
      int t = 0; float wv = 0.f;
      if (EPI == 4) { t = tok[e * NTOK + rr]; wv = wgt[e * NTOK + rr]; }
      size_t orow = (size_t)(pfx + rr);
#pragma unroll
      for (int n = 0; n < 4; n++) {
        int col = nbase + wc * 64 + n * 16 + fr;
        float v = acc[m][n][j];
        if (EPI == 0) {
          g1[orow * ldg + col] = f2bf(v);
        } else if (EPI == 1) {
          float gv = bf2f(g1[orow * ldg + col]);
          float hv = (gv / (1.f + __expf(-gv))) * v;   // silu(g1)*g2
          hbuf[orow * ldg + col] = f2bf(hv);
        } else if (EPI == 2) {
          outF[(size_t)rr * ldo + col] = v;
        } else if (EPI == 3) {
          outF[(size_t)rr * ldo + col] += v;
        } else {
          unsafeAtomicAdd(&outF[(size_t)t * ldo + col], v * wv);
        }
      }
    }
  }
}

// ---------------- host ----------------
extern "C" void kernel_launch(void* const* d_in, const int* in_sizes, int n_in,
                              void* d_out, int out_size, void* d_ws, size_t ws_size,
                              hipStream_t stream)
{
  const float* x   = (const float*)d_in[0];
  const float* gw  = (const float*)d_in[1];
  const float* ew1 = (const float*)d_in[2];
  const float* ew2 = (const float*)d_in[3];
  const float* ewp = (const float*)d_in[4];
  const float* sw1 = (const float*)d_in[5];
  const float* sw2 = (const float*)d_in[6];
  const float* swp = (const float*)d_in[7];
  float* out    = (float*)d_out;
  float* scores = out + (size_t)NTOK * CDIM;

  char* wsp = (char*)d_ws;
  size_t off = 0;
  auto alloc = [&](size_t bytes) -> void* {
    void* p = wsp + off; off += (bytes + 255) & ~(size_t)255; return p;
  };
  u16* xb   = (u16*)alloc((size_t)NTOK * CDIM * 2);
  u16* ew1t = (u16*)alloc((size_t)NEXP * FEDIM * CDIM * 2);
  u16* ew2t = (u16*)alloc((size_t)NEXP * FEDIM * CDIM * 2);
  u16* ewpt = (u16*)alloc((size_t)NEXP * CDIM * FEDIM * 2);
  u16* sw1t = (u16*)alloc((size_t)FSDIM * CDIM * 2);
  u16* sw2t = (u16*)alloc((size_t)FSDIM * CDIM * 2);
  u16* swpt = (u16*)alloc((size_t)CDIM * FSDIM * 2);
  u16* g1   = (u16*)alloc((size_t)2 * NTOK * 1024 * 2);   // 16384 x 1024 bf16
  u16* hbuf = (u16*)alloc((size_t)2 * NTOK * 1024 * 2);
  int* cnt  = (int*)alloc(256);
  int* pfx  = (int*)alloc(256);
  int* tok  = (int*)alloc((size_t)NEXP * NTOK * 4);
  float* wgt = (float*)alloc((size_t)NEXP * NTOK * 4);
  if (off > ws_size) return;  // workspace too small -> will show as full-absmax fail

  hipMemsetAsync(cnt, 0, 32, stream);
  gate_kernel<<<NTOK / 32, 256, 0, stream>>>(x, gw, scores, xb, cnt, tok, wgt);
  prefix_kernel<<<1, 64, 0, stream>>>(cnt, pfx);
  transpose_kernel<<<dim3(FEDIM/32, CDIM/32, NEXP), 256, 0, stream>>>(ew1, ew1t, CDIM, FEDIM);
  transpose_kernel<<<dim3(FEDIM/32, CDIM/32, NEXP), 256, 0, stream>>>(ew2, ew2t, CDIM, FEDIM);
  transpose_kernel<<<dim3(CDIM/32, FEDIM/32, NEXP), 256, 0, stream>>>(ewp, ewpt, FEDIM, CDIM);
  transpose_kernel<<<dim3(FSDIM/32, CDIM/32, 1), 256, 0, stream>>>(sw1, sw1t, CDIM, FSDIM);
  transpose_kernel<<<dim3(FSDIM/32, CDIM/32, 1), 256, 0, stream>>>(sw2, sw2t, CDIM, FSDIM);
  transpose_kernel<<<dim3(CDIM/32, FSDIM/32, 1), 256, 0, stream>>>(swp, swpt, FSDIM, CDIM);

  // shared FFN in two FS-slices of 2048 (reuses g1/hbuf)
  for (int s = 0; s < 2; s++) {
    const u16* b1 = sw1t + (size_t)s * 2048 * CDIM;
    const u16* b2 = sw2t + (size_t)s * 2048 * CDIM;
    const u16* bp = swpt + (size_t)s * 2048;
    gemm128<0,0><<<dim3(16, 64, 1), 256, 0, stream>>>(xb, CDIM, b1, 0, CDIM, NTOK, CDIM,
        g1, nullptr, 2048, nullptr, 0, nullptr, nullptr, nullptr, nullptr);
    gemm128<1,0><<<dim3(16, 64, 1), 256, 0, stream>>>(xb, CDIM, b2, 0, CDIM, NTOK, CDIM,
        g1, hbuf, 2048, nullptr, 0, nullptr, nullptr, nullptr, nullptr);
    if (s == 0)
      gemm128<2,0><<<dim3(8, 64, 1), 256, 0, stream>>>(hbuf, 2048, bp, 0, FSDIM, NTOK, 2048,
          nullptr, nullptr, 0, out, CDIM, nullptr, nullptr, nullptr, nullptr);
    else
      gemm128<3,0><<<dim3(8, 64, 1), 256, 0, stream>>>(hbuf, 2048, bp, 0, FSDIM, NTOK, 2048,
          nullptr, nullptr, 0, out, CDIM, nullptr, nullptr, nullptr, nullptr);
  }

  // experts on gathered (compacted) rows
  size_t estride = (size_t)FEDIM * CDIM;
  gemm128<0,1><<<dim3(8, 64, NEXP), 256, 0, stream>>>(xb, CDIM, ew1t, estride, CDIM, 0, CDIM,
      g1, nullptr, FEDIM, nullptr, 0, cnt, pfx, tok, wgt);
  gemm128<1,1><<<dim3(8, 64, NEXP), 256, 0, stream>>>(xb, CDIM, ew2t, estride, CDIM, 0, CDIM,
      g1, hbuf, FEDIM, nullptr, 0, cnt, pfx, tok, wgt);
  gemm128<4,2><<<dim3(8, 64, NEXP), 256, 0, stream>>>(hbuf, FEDIM, ewpt, estride, FEDIM, 0, FEDIM,
      nullptr, nullptr, 0, out, CDIM, cnt, pfx, tok, wgt);
}

// Round 3
// 822.892 us; speedup vs baseline: 1.4120x; 1.4120x over previous
//
#include <hip/hip_runtime.h>

typedef unsigned short u16;
typedef unsigned int u32;
typedef __bf16 bf16x8 __attribute__((ext_vector_type(8)));
typedef float f32x4 __attribute__((ext_vector_type(4)));
typedef u16 u16x8 __attribute__((ext_vector_type(8)));

#define NTOK 8192
#define CDIM 1024
#define NEXP 8
#define FEDIM 1024
#define FSDIM 4096

#define GLD16(gp, lp) __builtin_amdgcn_global_load_lds( \
    (const __attribute__((address_space(1))) void*)(gp), \
    (__attribute__((address_space(3))) void*)(lp), 16, 0, 0)

__device__ __forceinline__ u16 f2bf(float f) {
  u32 u = __float_as_uint(f);
  u += 0x7FFFu + ((u >> 16) & 1u);   // RNE
  return (u16)(u >> 16);
}
__device__ __forceinline__ float bf2f(u16 h) {
  return __uint_as_float(((u32)h) << 16);
}

// ---------------- gate: scores, softmax, top-2, expert lists, x->bf16 -------
// Block-local LDS aggregation; 8 global atomics per BLOCK (chunk reserve).
__global__ __launch_bounds__(256) void gate_kernel(
    const float* __restrict__ x, const float* __restrict__ gw,
    float* __restrict__ scores, u16* __restrict__ xb, int* __restrict__ cnt,
    int* __restrict__ tok, float* __restrict__ wgt)
{
  __shared__ int lcnt[NEXP];
  __shared__ int lbase[NEXP];
  __shared__ int rec_i[32];
  __shared__ int rec_p1[32], rec_p2[32];
  __shared__ float rec_w1[32], rec_w2[32];

  int tid = threadIdx.x, wave = tid >> 6, lane = tid & 63;
  if (tid < NEXP) lcnt[tid] = 0;
  __syncthreads();

  int tbase = blockIdx.x * 32 + wave * 8;
#pragma unroll
  for (int it = 0; it < 8; ++it) {
    int n = tbase + it;
    const float4* xr = (const float4*)(x + (size_t)n * CDIM) + lane * 4;
    float4 xv[4];
#pragma unroll
    for (int j = 0; j < 4; j++) xv[j] = xr[j];
    u16x8 rA, rB;
    rA[0]=f2bf(xv[0].x); rA[1]=f2bf(xv[0].y); rA[2]=f2bf(xv[0].z); rA[3]=f2bf(xv[0].w);
    rA[4]=f2bf(xv[1].x); rA[5]=f2bf(xv[1].y); rA[6]=f2bf(xv[1].z); rA[7]=f2bf(xv[1].w);
    rB[0]=f2bf(xv[2].x); rB[1]=f2bf(xv[2].y); rB[2]=f2bf(xv[2].z); rB[3]=f2bf(xv[2].w);
    rB[4]=f2bf(xv[3].x); rB[5]=f2bf(xv[3].y); rB[6]=f2bf(xv[3].z); rB[7]=f2bf(xv[3].w);
    u16* xrow = xb + (size_t)n * CDIM + lane * 16;
    *(u16x8*)xrow = rA;
    *(u16x8*)(xrow + 8) = rB;

    float s[NEXP];
#pragma unroll
    for (int e = 0; e < NEXP; e++) {
      const float4* g = (const float4*)(gw + (size_t)e * CDIM) + lane * 4;
      float a = 0.f;
#pragma unroll
      for (int j = 0; j < 4; j++) {
        float4 gv = g[j];
        a += xv[j].x * gv.x + xv[j].y * gv.y + xv[j].z * gv.z + xv[j].w * gv.w;
      }
#pragma unroll
      for (int o = 32; o > 0; o >>= 1) a += __shfl_xor(a, o);
      s[e] = a;
    }
    if (lane == 0) {
      float m = s[0];
      for (int e = 1; e < NEXP; e++) m = fmaxf(m, s[e]);
      float p[NEXP], sum = 0.f;
      for (int e = 0; e < NEXP; e++) { p[e] = __expf(s[e] - m); sum += p[e]; }
      int i1 = 0;
      for (int e = 1; e < NEXP; e++) if (p[e] > p[i1]) i1 = e;
      int i2 = (i1 == 0) ? 1 : 0;
      for (int e = 0; e < NEXP; e++) if (e != i1 && p[e] > p[i2]) i2 = e;
      float w1 = p[i1] / sum, w2 = p[i2] / sum;
#pragma unroll
      for (int e = 0; e < NEXP; e++) scores[(size_t)n * NEXP + e] = s[e];
      int p1 = atomicAdd(&lcnt[i1], 1);
      int p2 = atomicAdd(&lcnt[i2], 1);
      int slot = wave * 8 + it;
      rec_i[slot] = i1 | (i2 << 8);
      rec_p1[slot] = p1; rec_p2[slot] = p2;
      rec_w1[slot] = w1; rec_w2[slot] = w2;
    }
  }
  __syncthreads();
  if (tid < NEXP) lbase[tid] = atomicAdd(&cnt[tid], lcnt[tid]);
  __syncthreads();
  if (tid < 32) {
    int n = blockIdx.x * 32 + tid;
    int i1 = rec_i[tid] & 0xff, i2 = rec_i[tid] >> 8;
    int q1 = lbase[i1] + rec_p1[tid];
    int q2 = lbase[i2] + rec_p2[tid];
    tok[i1 * NTOK + q1] = n; wgt[i1 * NTOK + q1] = rec_w1[tid];
    tok[i2 * NTOK + q2] = n; wgt[i2 * NTOK + q2] = rec_w2[tid];
  }
}

__global__ void prefix_kernel(const int* __restrict__ cnt, int* __restrict__ prefix) {
  if (threadIdx.x == 0 && blockIdx.x == 0) {
    int a = 0;
    for (int e = 0; e < NEXP; e++) { prefix[e] = a; a += cnt[e]; }
    prefix[NEXP] = a;
  }
}

// ---------------- tiled transpose f32[R][C] -> bf16[C][R], batched in z ------
__global__ __launch_bounds__(256) void transpose_kernel(const float* __restrict__ src,
    u16* __restrict__ dst, int R, int C)
{
  __shared__ float tile[32][33];
  size_t base = (size_t)blockIdx.z * R * C;
  int c0 = blockIdx.x * 32, r0 = blockIdx.y * 32;
  int tx = threadIdx.x & 31, ty = threadIdx.x >> 5;
#pragma unroll
  for (int i = 0; i < 4; i++) {
    int r = ty + i * 8;
    tile[r][tx] = src[base + (size_t)(r0 + r) * C + c0 + tx];
  }
  __syncthreads();
#pragma unroll
  for (int i = 0; i < 4; i++) {
    int c = ty + i * 8;
    dst[base + (size_t)(c0 + c) * R + r0 + tx] = f2bf(tile[tx][c]);
  }
}

#define BM 128
#define BN 128
#define BK 32

// ---------------- fused SwiGLU GEMM: H = silu(A@B1^T) * (A@B2^T) -------------
// A bf16 [*, lda] row-major; B1/B2 in B^T layout [ncols][ldb]. One A-tile
// staged per k-step feeds 32 MFMAs (2 accumulator sets) -> 2x arithmetic
// intensity vs separate g1/g2 GEMMs, and no g1 round-trip through HBM.
// AMODE 0: direct rows; 1: rows gathered via tok list, H written compacted.
template<int AMODE>
__global__ __launch_bounds__(256) void gemm_swiglu(
    const u16* __restrict__ A, int lda,
    const u16* __restrict__ B1, const u16* __restrict__ B2,
    size_t bstride, int ldb,
    int M, int K,
    u16* __restrict__ H, int ldh,
    const int* __restrict__ cnt, const int* __restrict__ prefix,
    const int* __restrict__ tok)
{
  int e = blockIdx.z;
  int Mloc = (AMODE == 0) ? M : cnt[e];
  int mbase = blockIdx.y * BM;
  if (AMODE != 0 && mbase >= Mloc) return;
  int nbase = blockIdx.x * BN;
  int tid = threadIdx.x, wid = tid >> 6, lane = tid & 63;

  __shared__ __align__(16) u16 As[BM * BK];
  __shared__ __align__(16) u16 Bs1[BN * BK];
  __shared__ __align__(16) u16 Bs2[BN * BK];

  int sr = lane >> 2;             // 0..15 row within 16-row staging group
  int kg = (lane & 3) * 8;        // 8 bf16 = 16B per lane
  int arow0 = wid * 32 + sr;
  int arow1 = arow0 + 16;

  int pfx = (AMODE == 0) ? 0 : prefix[e];
  size_t r0, r1;
  if (AMODE == 0) {
    r0 = mbase + arow0; r1 = mbase + arow1;
  } else {
    r0 = tok[e * NTOK + min(mbase + arow0, Mloc - 1)];
    r1 = tok[e * NTOK + min(mbase + arow1, Mloc - 1)];
  }
  const u16* Ap0 = A + r0 * (size_t)lda + kg;
  const u16* Ap1 = A + r1 * (size_t)lda + kg;
  size_t boff = (AMODE != 0) ? (size_t)e * bstride : 0;
  const u16* B1p0 = B1 + boff + (size_t)(nbase + arow0) * ldb + kg;
  const u16* B1p1 = B1 + boff + (size_t)(nbase + arow1) * ldb + kg;
  const u16* B2p0 = B2 + boff + (size_t)(nbase + arow0) * ldb + kg;
  const u16* B2p1 = B2 + boff + (size_t)(nbase + arow1) * ldb + kg;

  u16* AsW0 = &As [(wid * 32) * BK];
  u16* AsW1 = &As [(wid * 32 + 16) * BK];
  u16* B1W0 = &Bs1[(wid * 32) * BK];
  u16* B1W1 = &Bs1[(wid * 32 + 16) * BK];
  u16* B2W0 = &Bs2[(wid * 32) * BK];
  u16* B2W1 = &Bs2[(wid * 32 + 16) * BK];

  int wr = wid >> 1, wc = wid & 1;
  int fr = lane & 15, fgk = (lane >> 4) * 8;

  f32x4 acc1[4][4] = {};
  f32x4 acc2[4][4] = {};

  for (int k0 = 0; k0 < K; k0 += BK) {
    GLD16(Ap0, AsW0);  GLD16(Ap1, AsW1);
    GLD16(B1p0, B1W0); GLD16(B1p1, B1W1);
    GLD16(B2p0, B2W0); GLD16(B2p1, B2W1);
    Ap0 += BK; Ap1 += BK; B1p0 += BK; B1p1 += BK; B2p0 += BK; B2p1 += BK;
    __syncthreads();
    bf16x8 af[4], b1f[4], b2f[4];
#pragma unroll
    for (int m = 0; m < 4; m++)
      af[m] = *(const bf16x8*)&As[(wr * 64 + m * 16 + fr) * BK + fgk];
#pragma unroll
    for (int n = 0; n < 4; n++) {
      b1f[n] = *(const bf16x8*)&Bs1[(wc * 64 + n * 16 + fr) * BK + fgk];
      b2f[n] = *(const bf16x8*)&Bs2[(wc * 64 + n * 16 + fr) * BK + fgk];
    }
#pragma unroll
    for (int m = 0; m < 4; m++)
#pragma unroll
      for (int n = 0; n < 4; n++) {
        acc1[m][n] = __builtin_amdgcn_mfma_f32_16x16x32_bf16(af[m], b1f[n], acc1[m][n], 0, 0, 0);
        acc2[m][n] = __builtin_amdgcn_mfma_f32_16x16x32_bf16(af[m], b2f[n], acc2[m][n], 0, 0, 0);
      }
    __syncthreads();
  }

  // epilogue — C/D layout: col = lane&15, row = (lane>>4)*4 + j
  int fg4 = (lane >> 4) * 4;
#pragma unroll
  for (int m = 0; m < 4; m++) {
#pragma unroll
    for (int j = 0; j < 4; j++) {
      int rloc = wr * 64 + m * 16 + fg4 + j;
      int rr = mbase + rloc;
      if (AMODE != 0 && rr >= Mloc) continue;
      size_t orow = (size_t)(pfx + rr);
#pragma unroll
      for (int n = 0; n < 4; n++) {
        int col = nbase + wc * 64 + n * 16 + fr;
        float g = acc1[m][n][j];
        float v = acc2[m][n][j];
        float hv = (g / (1.f + __expf(-g))) * v;   // silu(g)*v
        H[orow * (size_t)ldh + col] = f2bf(hv);
      }
    }
  }
}

// ---------------- proj GEMM (m97 structure, identity block mapping) ----------
// EPI: 2 store f32, 4 scale-by-weight + atomicAdd scatter to out rows tok[].
// AMODE: 0 direct rows, 2 rows at prefix[e]+r (compacted expert h).
template<int EPI, int AMODE>
__global__ __launch_bounds__(256) void gemm_proj(
    const u16* __restrict__ A, int lda,
    const u16* __restrict__ B, size_t bstride, int ldb,
    int M, int K,
    float* __restrict__ outF, int ldo,
    const int* __restrict__ cnt, const int* __restrict__ prefix,
    const int* __restrict__ tok, const float* __restrict__ wgt)
{
  int e = blockIdx.z;
  int Mloc = (AMODE == 0) ? M : cnt[e];
  int mbase = blockIdx.y * BM;
  if (AMODE != 0 && mbase >= Mloc) return;
  int nbase = blockIdx.x * BN;
  int tid = threadIdx.x, wid = tid >> 6, lane = tid & 63;

  __shared__ __align__(16) u16 As[BM * BK];
  __shared__ __align__(16) u16 Bs[BM * BK];

  int sr = lane >> 2;
  int kg = (lane & 3) * 8;
  int arow0 = wid * 32 + sr;
  int arow1 = arow0 + 16;

  int pfx = (AMODE == 0) ? 0 : prefix[e];
  size_t r0, r1;
  if (AMODE == 0) {
    r0 = mbase + arow0; r1 = mbase + arow1;
  } else {
    r0 = pfx + min(mbase + arow0, Mloc - 1);
    r1 = pfx + min(mbase + arow1, Mloc - 1);
  }
  const u16* Ap0 = A + r0 * (size_t)lda + kg;
  const u16* Ap1 = A + r1 * (size_t)lda + kg;
  const u16* Bb = B + ((AMODE != 0) ? (size_t)e * bstride : 0);
  const u16* Bp0 = Bb + (size_t)(nbase + arow0) * ldb + kg;
  const u16* Bp1 = Bb + (size_t)(nbase + arow1) * ldb + kg;

  u16* AsW0 = &As[(wid * 32) * BK];
  u16* AsW1 = &As[(wid * 32 + 16) * BK];
  u16* BsW0 = &Bs[(wid * 32) * BK];
  u16* BsW1 = &Bs[(wid * 32 + 16) * BK];

  int wr = wid >> 1, wc = wid & 1;
  int fr = lane & 15, fgk = (lane >> 4) * 8;

  f32x4 acc[4][4] = {};

  for (int k0 = 0; k0 < K; k0 += BK) {
    GLD16(Ap0, AsW0); GLD16(Ap1, AsW1);
    GLD16(Bp0, BsW0); GLD16(Bp1, BsW1);
    Ap0 += BK; Ap1 += BK; Bp0 += BK; Bp1 += BK;
    __syncthreads();
    bf16x8 af[4], bfr[4];
#pragma unroll
    for (int m = 0; m < 4; m++)
      af[m] = *(const bf16x8*)&As[(wr * 64 + m * 16 + fr) * BK + fgk];
#pragma unroll
    for (int n = 0; n < 4; n++)
      bfr[n] = *(const bf16x8*)&Bs[(wc * 64 + n * 16 + fr) * BK + fgk];
#pragma unroll
    for (int m = 0; m < 4; m++)
#pragma unroll
      for (int n = 0; n < 4; n++)
        acc[m][n] = __builtin_amdgcn_mfma_f32_16x16x32_bf16(af[m], bfr[n], acc[m][n], 0, 0, 0);
    __syncthreads();
  }

  int fg4 = (lane >> 4) * 4;
#pragma unroll
  for (int m = 0; m < 4; m++) {
#pragma unroll
    for (int j = 0; j < 4; j++) {
      int rloc = wr * 64 + m * 16 + fg4 + j;
      int rr = mbase + rloc;
      if (AMODE != 0 && rr >= Mloc) continue;
      int t = 0; float wv = 0.f;
      if (EPI == 4) { t = tok[e * NTOK + rr]; wv = wgt[e * NTOK + rr]; }
#pragma unroll
      for (int n = 0; n < 4; n++) {
        int col = nbase + wc * 64 + n * 16 + fr;
        float v = acc[m][n][j];
        if (EPI == 2) {
          outF[(size_t)rr * ldo + col] = v;
        } else {
          unsafeAtomicAdd(&outF[(size_t)t * ldo + col], v * wv);
        }
      }
    }
  }
}

// ---------------- host ----------------
extern "C" void kernel_launch(void* const* d_in, const int* in_sizes, int n_in,
                              void* d_out, int out_size, void* d_ws, size_t ws_size,
                              hipStream_t stream)
{
  const float* x   = (const float*)d_in[0];
  const float* gw  = (const float*)d_in[1];
  const float* ew1 = (const float*)d_in[2];
  const float* ew2 = (const float*)d_in[3];
  const float* ewp = (const float*)d_in[4];
  const float* sw1 = (const float*)d_in[5];
  const float* sw2 = (const float*)d_in[6];
  const float* swp = (const float*)d_in[7];
  float* out    = (float*)d_out;
  float* scores = out + (size_t)NTOK * CDIM;

  char* wsp = (char*)d_ws;
  size_t off = 0;
  auto alloc = [&](size_t bytes) -> void* {
    void* p = wsp + off; off += (bytes + 255) & ~(size_t)255; return p;
  };
  u16* xb   = (u16*)alloc((size_t)NTOK * CDIM * 2);
  u16* ew1t = (u16*)alloc((size_t)NEXP * FEDIM * CDIM * 2);
  u16* ew2t = (u16*)alloc((size_t)NEXP * FEDIM * CDIM * 2);
  u16* ewpt = (u16*)alloc((size_t)NEXP * CDIM * FEDIM * 2);
  u16* sw1t = (u16*)alloc((size_t)FSDIM * CDIM * 2);
  u16* sw2t = (u16*)alloc((size_t)FSDIM * CDIM * 2);
  u16* swpt = (u16*)alloc((size_t)CDIM * FSDIM * 2);
  u16* hs   = (u16*)alloc((size_t)NTOK * FSDIM * 2);      // shared h: 64 MB
  u16* he   = (u16*)alloc((size_t)2 * NTOK * FEDIM * 2);  // expert h (compacted): 32 MB
  int* cnt  = (int*)alloc(256);
  int* pfx  = (int*)alloc(256);
  int* tok  = (int*)alloc((size_t)NEXP * NTOK * 4);
  float* wgt = (float*)alloc((size_t)NEXP * NTOK * 4);
  if (off > ws_size) return;

  hipMemsetAsync(cnt, 0, 32, stream);
  gate_kernel<<<NTOK / 32, 256, 0, stream>>>(x, gw, scores, xb, cnt, tok, wgt);
  prefix_kernel<<<1, 64, 0, stream>>>(cnt, pfx);
  transpose_kernel<<<dim3(FEDIM/32, CDIM/32, NEXP), 256, 0, stream>>>(ew1, ew1t, CDIM, FEDIM);
  transpose_kernel<<<dim3(FEDIM/32, CDIM/32, NEXP), 256, 0, stream>>>(ew2, ew2t, CDIM, FEDIM);
  transpose_kernel<<<dim3(CDIM/32, FEDIM/32, NEXP), 256, 0, stream>>>(ewp, ewpt, FEDIM, CDIM);
  transpose_kernel<<<dim3(FSDIM/32, CDIM/32, 1), 256, 0, stream>>>(sw1, sw1t, CDIM, FSDIM);
  transpose_kernel<<<dim3(FSDIM/32, CDIM/32, 1), 256, 0, stream>>>(sw2, sw2t, CDIM, FSDIM);
  transpose_kernel<<<dim3(CDIM/32, FSDIM/32, 1), 256, 0, stream>>>(swp, swpt, FSDIM, CDIM);

  // shared FFN: fused SwiGLU (N=4096, K=1024) then proj (N=1024, K=4096)
  gemm_swiglu<0><<<dim3(FSDIM/BN, NTOK/BM, 1), 256, 0, stream>>>(
      xb, CDIM, sw1t, sw2t, 0, CDIM, NTOK, CDIM, hs, FSDIM, nullptr, nullptr, nullptr);
  gemm_proj<2,0><<<dim3(CDIM/BN, NTOK/BM, 1), 256, 0, stream>>>(
      hs, FSDIM, swpt, 0, FSDIM, NTOK, FSDIM, out, CDIM, nullptr, nullptr, nullptr, nullptr);

  // experts: fused SwiGLU on gathered rows, then proj with weighted scatter
  size_t estride = (size_t)FEDIM * CDIM;
  gemm_swiglu<1><<<dim3(FEDIM/BN, NTOK/BM, NEXP), 256, 0, stream>>>(
      xb, CDIM, ew1t, ew2t, estride, CDIM, 0, CDIM, he, FEDIM, cnt, pfx, tok);
  gemm_proj<4,2><<<dim3(CDIM/BN, NTOK/BM, NEXP), 256, 0, stream>>>(
      he, FEDIM, ewpt, estride, FEDIM, 0, FEDIM, out, CDIM, cnt, pfx, tok, wgt);
}

// Round 4
// 576.821 us; speedup vs baseline: 2.0143x; 1.4266x over previous
//
#include <hip/hip_runtime.h>

typedef unsigned short u16;
typedef unsigned int u32;
typedef __bf16 bf16x8 __attribute__((ext_vector_type(8)));
typedef float f32x4 __attribute__((ext_vector_type(4)));
typedef u16 u16x8 __attribute__((ext_vector_type(8)));

#define NTOK 8192
#define CDIM 1024
#define NEXP 8
#define FEDIM 1024
#define FSDIM 4096

#define GLD16(gp, lp) __builtin_amdgcn_global_load_lds( \
    (const __attribute__((address_space(1))) void*)(gp), \
    (__attribute__((address_space(3))) void*)(lp), 16, 0, 0)

__device__ __forceinline__ u16 f2bf(float f) {
  u32 u = __float_as_uint(f);
  u += 0x7FFFu + ((u >> 16) & 1u);   // RNE
  return (u16)(u >> 16);
}
__device__ __forceinline__ float bf2f(u16 h) {
  return __uint_as_float(((u32)h) << 16);
}

// ---------------- gate: scores, softmax, top-2, expert lists, x->bf16 -------
__global__ __launch_bounds__(256) void gate_kernel(
    const float* __restrict__ x, const float* __restrict__ gw,
    float* __restrict__ scores, u16* __restrict__ xb, int* __restrict__ cnt,
    int* __restrict__ tok, float* __restrict__ wgt)
{
  __shared__ int lcnt[NEXP];
  __shared__ int lbase[NEXP];
  __shared__ int rec_i[32];
  __shared__ int rec_p1[32], rec_p2[32];
  __shared__ float rec_w1[32], rec_w2[32];

  int tid = threadIdx.x, wave = tid >> 6, lane = tid & 63;
  if (tid < NEXP) lcnt[tid] = 0;
  __syncthreads();

  int tbase = blockIdx.x * 32 + wave * 8;
#pragma unroll
  for (int it = 0; it < 8; ++it) {
    int n = tbase + it;
    const float4* xr = (const float4*)(x + (size_t)n * CDIM) + lane * 4;
    float4 xv[4];
#pragma unroll
    for (int j = 0; j < 4; j++) xv[j] = xr[j];
    u16x8 rA, rB;
    rA[0]=f2bf(xv[0].x); rA[1]=f2bf(xv[0].y); rA[2]=f2bf(xv[0].z); rA[3]=f2bf(xv[0].w);
    rA[4]=f2bf(xv[1].x); rA[5]=f2bf(xv[1].y); rA[6]=f2bf(xv[1].z); rA[7]=f2bf(xv[1].w);
    rB[0]=f2bf(xv[2].x); rB[1]=f2bf(xv[2].y); rB[2]=f2bf(xv[2].z); rB[3]=f2bf(xv[2].w);
    rB[4]=f2bf(xv[3].x); rB[5]=f2bf(xv[3].y); rB[6]=f2bf(xv[3].z); rB[7]=f2bf(xv[3].w);
    u16* xrow = xb + (size_t)n * CDIM + lane * 16;
    *(u16x8*)xrow = rA;
    *(u16x8*)(xrow + 8) = rB;

    float s[NEXP];
#pragma unroll
    for (int e = 0; e < NEXP; e++) {
      const float4* g = (const float4*)(gw + (size_t)e * CDIM) + lane * 4;
      float a = 0.f;
#pragma unroll
      for (int j = 0; j < 4; j++) {
        float4 gv = g[j];
        a += xv[j].x * gv.x + xv[j].y * gv.y + xv[j].z * gv.z + xv[j].w * gv.w;
      }
#pragma unroll
      for (int o = 32; o > 0; o >>= 1) a += __shfl_xor(a, o);
      s[e] = a;
    }
    if (lane == 0) {
      float m = s[0];
      for (int e = 1; e < NEXP; e++) m = fmaxf(m, s[e]);
      float p[NEXP], sum = 0.f;
      for (int e = 0; e < NEXP; e++) { p[e] = __expf(s[e] - m); sum += p[e]; }
      int i1 = 0;
      for (int e = 1; e < NEXP; e++) if (p[e] > p[i1]) i1 = e;
      int i2 = (i1 == 0) ? 1 : 0;
      for (int e = 0; e < NEXP; e++) if (e != i1 && p[e] > p[i2]) i2 = e;
      float w1 = p[i1] / sum, w2 = p[i2] / sum;
#pragma unroll
      for (int e = 0; e < NEXP; e++) scores[(size_t)n * NEXP + e] = s[e];
      int p1 = atomicAdd(&lcnt[i1], 1);
      int p2 = atomicAdd(&lcnt[i2], 1);
      int slot = wave * 8 + it;
      rec_i[slot] = i1 | (i2 << 8);
      rec_p1[slot] = p1; rec_p2[slot] = p2;
      rec_w1[slot] = w1; rec_w2[slot] = w2;
    }
  }
  __syncthreads();
  if (tid < NEXP) lbase[tid] = atomicAdd(&cnt[tid], lcnt[tid]);
  __syncthreads();
  if (tid < 32) {
    int n = blockIdx.x * 32 + tid;
    int i1 = rec_i[tid] & 0xff, i2 = rec_i[tid] >> 8;
    int q1 = lbase[i1] + rec_p1[tid];
    int q2 = lbase[i2] + rec_p2[tid];
    tok[i1 * NTOK + q1] = n; wgt[i1 * NTOK + q1] = rec_w1[tid];
    tok[i2 * NTOK + q2] = n; wgt[i2 * NTOK + q2] = rec_w2[tid];
  }
}

__global__ void prefix_kernel(const int* __restrict__ cnt, int* __restrict__ prefix) {
  if (threadIdx.x == 0 && blockIdx.x == 0) {
    int a = 0;
    for (int e = 0; e < NEXP; e++) { prefix[e] = a; a += cnt[e]; }
    prefix[NEXP] = a;
  }
}

// ---------------- tiled transpose f32[R][C] -> bf16[C][R], batched in z ------
__global__ __launch_bounds__(256) void transpose_kernel(const float* __restrict__ src,
    u16* __restrict__ dst, int R, int C)
{
  __shared__ float tile[32][33];
  size_t base = (size_t)blockIdx.z * R * C;
  int c0 = blockIdx.x * 32, r0 = blockIdx.y * 32;
  int tx = threadIdx.x & 31, ty = threadIdx.x >> 5;
#pragma unroll
  for (int i = 0; i < 4; i++) {
    int r = ty + i * 8;
    tile[r][tx] = src[base + (size_t)(r0 + r) * C + c0 + tx];
  }
  __syncthreads();
#pragma unroll
  for (int i = 0; i < 4; i++) {
    int c = ty + i * 8;
    dst[base + (size_t)(c0 + c) * R + r0 + tx] = f2bf(tile[tx][c]);
  }
}

#define BM 128
#define BN 128
#define BK 32
#define TILE (BM * BK)   // 4096 u16 = 8 KB

// ---------------- fused SwiGLU GEMM: H = silu(A@B1^T) * (A@B2^T) -------------
// Double-buffered LDS (T3-minimum 2-phase): stage tile t+1 into buf^1 BEFORE
// computing tile t; one full __syncthreads (vmcnt+lgkm drain) per k-step.
// __launch_bounds__(256,2): combined VGPR+AGPR <= 256 -> 2 waves/SIMD
// (round-3 was 264 -> 1 wave/SIMD -> zero latency hiding, MfmaUtil 17%).
template<int AMODE>
__global__ __launch_bounds__(256, 2) void gemm_swiglu(
    const u16* __restrict__ A, int lda,
    const u16* __restrict__ B1, const u16* __restrict__ B2,
    size_t bstride, int ldb,
    int M, int K,
    u16* __restrict__ H, int ldh,
    const int* __restrict__ cnt, const int* __restrict__ prefix,
    const int* __restrict__ tok)
{
  int e = blockIdx.z;
  int Mloc = (AMODE == 0) ? M : cnt[e];
  int mbase = blockIdx.y * BM;
  if (AMODE != 0 && mbase >= Mloc) return;
  int nbase = blockIdx.x * BN;
  int tid = threadIdx.x, wid = tid >> 6, lane = tid & 63;

  __shared__ __align__(16) u16 As[2][TILE];
  __shared__ __align__(16) u16 Bs1[2][TILE];
  __shared__ __align__(16) u16 Bs2[2][TILE];

  int sr = lane >> 2;             // 0..15 row within 16-row staging group
  int kg = (lane & 3) * 8;        // 8 bf16 = 16B per lane
  int arow0 = wid * 32 + sr;
  int arow1 = arow0 + 16;

  int pfx = (AMODE == 0) ? 0 : prefix[e];
  size_t r0, r1;
  if (AMODE == 0) {
    r0 = mbase + arow0; r1 = mbase + arow1;
  } else {
    r0 = tok[e * NTOK + min(mbase + arow0, Mloc - 1)];
    r1 = tok[e * NTOK + min(mbase + arow1, Mloc - 1)];
  }
  const u16* Ap0 = A + r0 * (size_t)lda + kg;
  const u16* Ap1 = A + r1 * (size_t)lda + kg;
  size_t boff = (AMODE != 0) ? (size_t)e * bstride : 0;
  const u16* B1p0 = B1 + boff + (size_t)(nbase + arow0) * ldb + kg;
  const u16* B1p1 = B1 + boff + (size_t)(nbase + arow1) * ldb + kg;
  const u16* B2p0 = B2 + boff + (size_t)(nbase + arow0) * ldb + kg;
  const u16* B2p1 = B2 + boff + (size_t)(nbase + arow1) * ldb + kg;

  int ldsw0 = (wid * 32) * BK;        // wave slice, rows [w*32, w*32+16)
  int ldsw1 = (wid * 32 + 16) * BK;   // rows [w*32+16, w*32+32)

  int wr = wid >> 1, wc = wid & 1;
  int fr = lane & 15, fgk = (lane >> 4) * 8;

  f32x4 acc1[4][4] = {};
  f32x4 acc2[4][4] = {};

  int nt = K / BK;
  // prologue: stage tile 0 into buffer 0
  GLD16(Ap0,  &As [0][ldsw0]); GLD16(Ap1,  &As [0][ldsw1]);
  GLD16(B1p0, &Bs1[0][ldsw0]); GLD16(B1p1, &Bs1[0][ldsw1]);
  GLD16(B2p0, &Bs2[0][ldsw0]); GLD16(B2p1, &Bs2[0][ldsw1]);
  Ap0 += BK; Ap1 += BK; B1p0 += BK; B1p1 += BK; B2p0 += BK; B2p1 += BK;
  __syncthreads();

  int cur = 0;
  for (int t = 0; t < nt; ++t) {
    int nxt = cur ^ 1;
    if (t + 1 < nt) {   // prefetch next tile into the idle buffer
      GLD16(Ap0,  &As [nxt][ldsw0]); GLD16(Ap1,  &As [nxt][ldsw1]);
      GLD16(B1p0, &Bs1[nxt][ldsw0]); GLD16(B1p1, &Bs1[nxt][ldsw1]);
      GLD16(B2p0, &Bs2[nxt][ldsw0]); GLD16(B2p1, &Bs2[nxt][ldsw1]);
      Ap0 += BK; Ap1 += BK; B1p0 += BK; B1p1 += BK; B2p0 += BK; B2p1 += BK;
    }
    const u16* as = As[cur];
    const u16* b1s = Bs1[cur];
    const u16* b2s = Bs2[cur];
    bf16x8 af[4], b1f[4], b2f[4];
#pragma unroll
    for (int m = 0; m < 4; m++)
      af[m] = *(const bf16x8*)&as[(wr * 64 + m * 16 + fr) * BK + fgk];
#pragma unroll
    for (int n = 0; n < 4; n++) {
      b1f[n] = *(const bf16x8*)&b1s[(wc * 64 + n * 16 + fr) * BK + fgk];
      b2f[n] = *(const bf16x8*)&b2s[(wc * 64 + n * 16 + fr) * BK + fgk];
    }
#pragma unroll
    for (int m = 0; m < 4; m++)
#pragma unroll
      for (int n = 0; n < 4; n++) {
        acc1[m][n] = __builtin_amdgcn_mfma_f32_16x16x32_bf16(af[m], b1f[n], acc1[m][n], 0, 0, 0);
        acc2[m][n] = __builtin_amdgcn_mfma_f32_16x16x32_bf16(af[m], b2f[n], acc2[m][n], 0, 0, 0);
      }
    __syncthreads();   // drains prefetch vmcnt + all lgkm; flip buffers
    cur = nxt;
  }

  // epilogue — C/D layout: col = lane&15, row = (lane>>4)*4 + j
  int fg4 = (lane >> 4) * 4;
#pragma unroll
  for (int m = 0; m < 4; m++) {
#pragma unroll
    for (int j = 0; j < 4; j++) {
      int rloc = wr * 64 + m * 16 + fg4 + j;
      int rr = mbase + rloc;
      if (AMODE != 0 && rr >= Mloc) continue;
      size_t orow = (size_t)(pfx + rr);
#pragma unroll
      for (int n = 0; n < 4; n++) {
        int col = nbase + wc * 64 + n * 16 + fr;
        float g = acc1[m][n][j];
        float v = acc2[m][n][j];
        float hv = (g / (1.f + __expf(-g))) * v;   // silu(g)*v
        H[orow * (size_t)ldh + col] = f2bf(hv);
      }
    }
  }
}

// ---------------- proj GEMM, double-buffered -------------------------------
// EPI: 2 store f32, 4 scale-by-weight + atomicAdd scatter to out rows tok[].
// AMODE: 0 direct rows, 2 rows at prefix[e]+r (compacted expert h).
template<int EPI, int AMODE>
__global__ __launch_bounds__(256, 2) void gemm_proj(
    const u16* __restrict__ A, int lda,
    const u16* __restrict__ B, size_t bstride, int ldb,
    int M, int K,
    float* __restrict__ outF, int ldo,
    const int* __restrict__ cnt, const int* __restrict__ prefix,
    const int* __restrict__ tok, const float* __restrict__ wgt)
{
  int e = blockIdx.z;
  int Mloc = (AMODE == 0) ? M : cnt[e];
  int mbase = blockIdx.y * BM;
  if (AMODE != 0 && mbase >= Mloc) return;
  int nbase = blockIdx.x * BN;
  int tid = threadIdx.x, wid = tid >> 6, lane = tid & 63;

  __shared__ __align__(16) u16 As[2][TILE];
  __shared__ __align__(16) u16 Bs[2][TILE];

  int sr = lane >> 2;
  int kg = (lane & 3) * 8;
  int arow0 = wid * 32 + sr;
  int arow1 = arow0 + 16;

  int pfx = (AMODE == 0) ? 0 : prefix[e];
  size_t r0, r1;
  if (AMODE == 0) {
    r0 = mbase + arow0; r1 = mbase + arow1;
  } else {
    r0 = pfx + min(mbase + arow0, Mloc - 1);
    r1 = pfx + min(mbase + arow1, Mloc - 1);
  }
  const u16* Ap0 = A + r0 * (size_t)lda + kg;
  const u16* Ap1 = A + r1 * (size_t)lda + kg;
  const u16* Bb = B + ((AMODE != 0) ? (size_t)e * bstride : 0);
  const u16* Bp0 = Bb + (size_t)(nbase + arow0) * ldb + kg;
  const u16* Bp1 = Bb + (size_t)(nbase + arow1) * ldb + kg;

  int ldsw0 = (wid * 32) * BK;
  int ldsw1 = (wid * 32 + 16) * BK;

  int wr = wid >> 1, wc = wid & 1;
  int fr = lane & 15, fgk = (lane >> 4) * 8;

  f32x4 acc[4][4] = {};

  int nt = K / BK;
  GLD16(Ap0, &As[0][ldsw0]); GLD16(Ap1, &As[0][ldsw1]);
  GLD16(Bp0, &Bs[0][ldsw0]); GLD16(Bp1, &Bs[0][ldsw1]);
  Ap0 += BK; Ap1 += BK; Bp0 += BK; Bp1 += BK;
  __syncthreads();

  int cur = 0;
  for (int t = 0; t < nt; ++t) {
    int nxt = cur ^ 1;
    if (t + 1 < nt) {
      GLD16(Ap0, &As[nxt][ldsw0]); GLD16(Ap1, &As[nxt][ldsw1]);
      GLD16(Bp0, &Bs[nxt][ldsw0]); GLD16(Bp1, &Bs[nxt][ldsw1]);
      Ap0 += BK; Ap1 += BK; Bp0 += BK; Bp1 += BK;
    }
    const u16* as = As[cur];
    const u16* bs = Bs[cur];
    bf16x8 af[4], bfr[4];
#pragma unroll
    for (int m = 0; m < 4; m++)
      af[m] = *(const bf16x8*)&as[(wr * 64 + m * 16 + fr) * BK + fgk];
#pragma unroll
    for (int n = 0; n < 4; n++)
      bfr[n] = *(const bf16x8*)&bs[(wc * 64 + n * 16 + fr) * BK + fgk];
#pragma unroll
    for (int m = 0; m < 4; m++)
#pragma unroll
      for (int n = 0; n < 4; n++)
        acc[m][n] = __builtin_amdgcn_mfma_f32_16x16x32_bf16(af[m], bfr[n], acc[m][n], 0, 0, 0);
    __syncthreads();
    cur = nxt;
  }

  int fg4 = (lane >> 4) * 4;
#pragma unroll
  for (int m = 0; m < 4; m++) {
#pragma unroll
    for (int j = 0; j < 4; j++) {
      int rloc = wr * 64 + m * 16 + fg4 + j;
      int rr = mbase + rloc;
      if (AMODE != 0 && rr >= Mloc) continue;
      int t = 0; float wv = 0.f;
      if (EPI == 4) { t = tok[e * NTOK + rr]; wv = wgt[e * NTOK + rr]; }
#pragma unroll
      for (int n = 0; n < 4; n++) {
        int col = nbase + wc * 64 + n * 16 + fr;
        float v = acc[m][n][j];
        if (EPI == 2) {
          outF[(size_t)rr * ldo + col] = v;
        } else {
          unsafeAtomicAdd(&outF[(size_t)t * ldo + col], v * wv);
        }
      }
    }
  }
}

// ---------------- host ----------------
extern "C" void kernel_launch(void* const* d_in, const int* in_sizes, int n_in,
                              void* d_out, int out_size, void* d_ws, size_t ws_size,
                              hipStream_t stream)
{
  const float* x   = (const float*)d_in[0];
  const float* gw  = (const float*)d_in[1];
  const float* ew1 = (const float*)d_in[2];
  const float* ew2 = (const float*)d_in[3];
  const float* ewp = (const float*)d_in[4];
  const float* sw1 = (const float*)d_in[5];
  const float* sw2 = (const float*)d_in[6];
  const float* swp = (const float*)d_in[7];
  float* out    = (float*)d_out;
  float* scores = out + (size_t)NTOK * CDIM;

  char* wsp = (char*)d_ws;
  size_t off = 0;
  auto alloc = [&](size_t bytes) -> void* {
    void* p = wsp + off; off += (bytes + 255) & ~(size_t)255; return p;
  };
  u16* xb   = (u16*)alloc((size_t)NTOK * CDIM * 2);
  u16* ew1t = (u16*)alloc((size_t)NEXP * FEDIM * CDIM * 2);
  u16* ew2t = (u16*)alloc((size_t)NEXP * FEDIM * CDIM * 2);
  u16* ewpt = (u16*)alloc((size_t)NEXP * CDIM * FEDIM * 2);
  u16* sw1t = (u16*)alloc((size_t)FSDIM * CDIM * 2);
  u16* sw2t = (u16*)alloc((size_t)FSDIM * CDIM * 2);
  u16* swpt = (u16*)alloc((size_t)CDIM * FSDIM * 2);
  u16* hs   = (u16*)alloc((size_t)NTOK * FSDIM * 2);      // shared h: 64 MB
  u16* he   = (u16*)alloc((size_t)2 * NTOK * FEDIM * 2);  // expert h (compacted): 32 MB
  int* cnt  = (int*)alloc(256);
  int* pfx  = (int*)alloc(256);
  int* tok  = (int*)alloc((size_t)NEXP * NTOK * 4);
  float* wgt = (float*)alloc((size_t)NEXP * NTOK * 4);
  if (off > ws_size) return;

  hipMemsetAsync(cnt, 0, 32, stream);
  gate_kernel<<<NTOK / 32, 256, 0, stream>>>(x, gw, scores, xb, cnt, tok, wgt);
  prefix_kernel<<<1, 64, 0, stream>>>(cnt, pfx);
  transpose_kernel<<<dim3(FEDIM/32, CDIM/32, NEXP), 256, 0, stream>>>(ew1, ew1t, CDIM, FEDIM);
  transpose_kernel<<<dim3(FEDIM/32, CDIM/32, NEXP), 256, 0, stream>>>(ew2, ew2t, CDIM, FEDIM);
  transpose_kernel<<<dim3(CDIM/32, FEDIM/32, NEXP), 256, 0, stream>>>(ewp, ewpt, FEDIM, CDIM);
  transpose_kernel<<<dim3(FSDIM/32, CDIM/32, 1), 256, 0, stream>>>(sw1, sw1t, CDIM, FSDIM);
  transpose_kernel<<<dim3(FSDIM/32, CDIM/32, 1), 256, 0, stream>>>(sw2, sw2t, CDIM, FSDIM);
  transpose_kernel<<<dim3(CDIM/32, FSDIM/32, 1), 256, 0, stream>>>(swp, swpt, FSDIM, CDIM);

  // shared FFN: fused SwiGLU (N=4096, K=1024) then proj (N=1024, K=4096)
  gemm_swiglu<0><<<dim3(FSDIM/BN, NTOK/BM, 1), 256, 0, stream>>>(
      xb, CDIM, sw1t, sw2t, 0, CDIM, NTOK, CDIM, hs, FSDIM, nullptr, nullptr, nullptr);
  gemm_proj<2,0><<<dim3(CDIM/BN, NTOK/BM, 1), 256, 0, stream>>>(
      hs, FSDIM, swpt, 0, FSDIM, NTOK, FSDIM, out, CDIM, nullptr, nullptr, nullptr, nullptr);

  // experts: fused SwiGLU on gathered rows, then proj with weighted scatter
  size_t estride = (size_t)FEDIM * CDIM;
  gemm_swiglu<1><<<dim3(FEDIM/BN, NTOK/BM, NEXP), 256, 0, stream>>>(
      xb, CDIM, ew1t, ew2t, estride, CDIM, 0, CDIM, he, FEDIM, cnt, pfx, tok);
  gemm_proj<4,2><<<dim3(CDIM/BN, NTOK/BM, NEXP), 256, 0, stream>>>(
      he, FEDIM, ewpt, estride, FEDIM, 0, FEDIM, out, CDIM, cnt, pfx, tok, wgt);
}